// Round 1
// baseline (440.203 us; speedup 1.0000x reference)
//
#include <hip/hip_runtime.h>
#include <hip/hip_bf16.h>
#include <stdint.h>

typedef __bf16 bf16x8 __attribute__((ext_vector_type(8)));
typedef float  f32x4  __attribute__((ext_vector_type(4)));

static constexpr float kScale = 0.0078125f;  // 1/128, exact in bf16/f32

// ---------- f32 -> bf16 (RNE) convert, 8 elems/thread ----------
static __device__ __forceinline__ uint32_t bf16_rne(float f) {
  uint32_t u = __builtin_bit_cast(uint32_t, f);
  u += 0x7FFFu + ((u >> 16) & 1u);
  return u >> 16;
}
static __device__ __forceinline__ uint32_t pack2(float lo, float hi) {
  return bf16_rne(lo) | (bf16_rne(hi) << 16);
}

__global__ __launch_bounds__(256) void cvt_f32_to_bf16(
    const float* __restrict__ src, uint4* __restrict__ dst) {
  const int i = blockIdx.x * 256 + threadIdx.x;
  const float4* sv = reinterpret_cast<const float4*>(src);
  float4 a = sv[2 * i];
  float4 b = sv[2 * i + 1];
  uint4 o;
  o.x = pack2(a.x, a.y);
  o.y = pack2(a.z, a.w);
  o.z = pack2(b.x, b.y);
  o.w = pack2(b.z, b.w);
  dst[i] = o;
}

// ---------- async global->LDS, 16B per lane ----------
static __device__ __forceinline__ void gload_lds16(const void* g, void* l) {
  __builtin_amdgcn_global_load_lds(
      (const __attribute__((address_space(1))) void*)g,
      (__attribute__((address_space(3))) void*)l, 16, 0, 0);
}

// ---------- bf16 GEMM, m97 structure: 128x128 tile, BK=32, 4 waves ----------
// A: [M][K] bf16 bits, B: [N][K] bf16 bits (torch Linear layout = B^T GEMM)
// C[m][n] = kScale * sum_k A[m][k]*B[n][k] + bias[n]
__global__ __launch_bounds__(256) void gemm_bf16_bias(
    const uint16_t* __restrict__ A, const uint16_t* __restrict__ B,
    const float* __restrict__ bias, float* __restrict__ C,
    int Mi, int Ni, int Ki) {
  __shared__ alignas(16) uint16_t As[128 * 32];  // 8 KB
  __shared__ alignas(16) uint16_t Bs[128 * 32];  // 8 KB

  const int tid  = threadIdx.x;
  const int lane = tid & 63;
  const int wv   = tid >> 6;
  const int wr   = wv >> 1;      // wave row (0..1) -> 64 rows each
  const int wc   = wv & 1;       // wave col (0..1) -> 64 cols each
  const int fr   = lane & 15;    // frag row (A) / col (B) / col (C)
  const int fh   = lane >> 4;    // 0..3: k-slot for A/B, row-group for C

  // bijective XCD-aware swizzle (gridDim.x % 8 == 0 here: 64*64=4096)
  const int nTilesN = Ni >> 7;
  const int cpx = gridDim.x >> 3;
  const int swz = ((int)blockIdx.x & 7) * cpx + ((int)blockIdx.x >> 3);
  const int bm = swz / nTilesN;
  const int bn = swz % nTilesN;

  // staging map: chunk c in {0,1}: elem e=(c*256+tid)*8; row=e/32; col=(tid&3)*8
  const int sRow = tid >> 2;
  const int sCol = (tid & 3) << 3;

  const uint16_t* gA0 = A + (size_t)(bm * 128 + sRow) * Ki + sCol;
  const uint16_t* gA1 = gA0 + (size_t)64 * Ki;
  const uint16_t* gB0 = B + (size_t)(bn * 128 + sRow) * Ki + sCol;
  const uint16_t* gB1 = gB0 + (size_t)64 * Ki;
  uint16_t* lA0 = &As[tid * 8];          // lds byte addr linear in lane (x16)
  uint16_t* lA1 = &As[(256 + tid) * 8];
  uint16_t* lB0 = &Bs[tid * 8];
  uint16_t* lB1 = &Bs[(256 + tid) * 8];

  const bf16x8* Av = reinterpret_cast<const bf16x8*>(As);
  const bf16x8* Bv = reinterpret_cast<const bf16x8*>(Bs);

  f32x4 acc[4][4] = {};

  for (int k0 = 0; k0 < Ki; k0 += 32) {
    gload_lds16(gA0 + k0, lA0);
    gload_lds16(gA1 + k0, lA1);
    gload_lds16(gB0 + k0, lB0);
    gload_lds16(gB1 + k0, lB1);
    __syncthreads();  // compiler drains vmcnt(0) before s_barrier -> tile ready

    bf16x8 af[4], bfr[4];
#pragma unroll
    for (int m = 0; m < 4; ++m)
      af[m] = Av[(wr * 64 + m * 16 + fr) * 4 + fh];
#pragma unroll
    for (int n = 0; n < 4; ++n)
      bfr[n] = Bv[(wc * 64 + n * 16 + fr) * 4 + fh];

#pragma unroll
    for (int m = 0; m < 4; ++m)
#pragma unroll
      for (int n = 0; n < 4; ++n)
        acc[m][n] = __builtin_amdgcn_mfma_f32_16x16x32_bf16(af[m], bfr[n],
                                                            acc[m][n], 0, 0, 0);
    __syncthreads();  // all frag reads done before next overwrite
  }

  // epilogue: C/D layout col=lane&15, row=(lane>>4)*4+j  [m89/m91 verified]
  const int rowBase = bm * 128 + wr * 64;
  const int colBase = bn * 128 + wc * 64;
#pragma unroll
  for (int n = 0; n < 4; ++n) {
    const int col = colBase + n * 16 + fr;
    const float bv = bias[col];
#pragma unroll
    for (int m = 0; m < 4; ++m) {
      const int row = rowBase + m * 16 + fh * 4;
#pragma unroll
      for (int j = 0; j < 4; ++j)
        C[(size_t)(row + j) * Ni + col] = acc[m][n][j] * kScale + bv;
    }
  }
}

// ---------- fallback (only if ws too small): naive f32 ----------
__global__ void naive_gemm(const float* __restrict__ x, const float* __restrict__ w,
                           const float* __restrict__ bias, float* __restrict__ out,
                           int Mi, int Ni, int Ki) {
  long idx = (long)blockIdx.x * blockDim.x + threadIdx.x;
  if (idx >= (long)Mi * Ni) return;
  int m = (int)(idx / Ni), n = (int)(idx % Ni);
  float s = 0.f;
  for (int k = 0; k < Ki; ++k) s += x[(long)m * Ki + k] * w[(long)n * Ki + k];
  out[idx] = s * kScale + bias[n];
}

extern "C" void kernel_launch(void* const* d_in, const int* in_sizes, int n_in,
                              void* d_out, int out_size, void* d_ws, size_t ws_size,
                              hipStream_t stream) {
  const float* x    = (const float*)d_in[0];
  const float* w    = (const float*)d_in[1];
  const float* bias = (const float*)d_in[2];
  float* out = (float*)d_out;

  const int Ni = in_sizes[2];            // 8192
  const int Ki = in_sizes[1] / Ni;       // 2048
  const int Mi = in_sizes[0] / Ki;       // 8192

  const size_t nx = (size_t)Mi * Ki;
  const size_t nw = (size_t)Ni * Ki;

  if (ws_size >= (nx + nw) * sizeof(uint16_t)) {
    uint16_t* xb = (uint16_t*)d_ws;
    uint16_t* wb = xb + nx;
    cvt_f32_to_bf16<<<(int)(nx / 2048), 256, 0, stream>>>(x, (uint4*)xb);
    cvt_f32_to_bf16<<<(int)(nw / 2048), 256, 0, stream>>>(w, (uint4*)wb);
    dim3 grid((Mi / 128) * (Ni / 128));
    gemm_bf16_bias<<<grid, 256, 0, stream>>>(xb, wb, bias, out, Mi, Ni, Ki);
  } else {
    long total = (long)Mi * Ni;
    naive_gemm<<<(int)((total + 255) / 256), 256, 0, stream>>>(x, w, bias, out,
                                                               Mi, Ni, Ki);
  }
}

// Round 2
// 372.458 us; speedup vs baseline: 1.1819x; 1.1819x over previous
//
#include <hip/hip_runtime.h>
#include <hip/hip_bf16.h>
#include <stdint.h>

typedef __bf16 bf16x8 __attribute__((ext_vector_type(8)));
typedef float  f32x4  __attribute__((ext_vector_type(4)));

static constexpr float kScale = 0.0078125f;  // 1/128

// ---------- f32 -> bf16 (RNE) convert, 8 elems/thread ----------
static __device__ __forceinline__ uint32_t bf16_rne(float f) {
  uint32_t u = __builtin_bit_cast(uint32_t, f);
  u += 0x7FFFu + ((u >> 16) & 1u);
  return u >> 16;
}
static __device__ __forceinline__ uint32_t pack2(float lo, float hi) {
  return bf16_rne(lo) | (bf16_rne(hi) << 16);
}

__global__ __launch_bounds__(256) void cvt_f32_to_bf16(
    const float* __restrict__ src, uint4* __restrict__ dst) {
  const int i = blockIdx.x * 256 + threadIdx.x;
  const float4* sv = reinterpret_cast<const float4*>(src);
  float4 a = sv[2 * i];
  float4 b = sv[2 * i + 1];
  uint4 o;
  o.x = pack2(a.x, a.y);
  o.y = pack2(a.z, a.w);
  o.z = pack2(b.x, b.y);
  o.w = pack2(b.z, b.w);
  dst[i] = o;
}

// ---------- async global->LDS, 16B per lane ----------
static __device__ __forceinline__ void gload_lds16(const void* g, void* l) {
  __builtin_amdgcn_global_load_lds(
      (const __attribute__((address_space(1))) void*)g,
      (__attribute__((address_space(3))) void*)l, 16, 0, 0);
}

#define BARRIER() __builtin_amdgcn_s_barrier()
#define LGKM0()                                        \
  do {                                                 \
    asm volatile("s_waitcnt lgkmcnt(0)" ::: "memory"); \
    __builtin_amdgcn_sched_barrier(0);                 \
  } while (0)
#define VM6()                                          \
  do {                                                 \
    asm volatile("s_waitcnt vmcnt(6)" ::: "memory");   \
    __builtin_amdgcn_sched_barrier(0);                 \
  } while (0)

// =====================================================================
// 256x256 tile, BK=64, 8-phase schedule (T2 swizzle + T3/T4 counted
// vmcnt + T5 setprio).  8 waves as 2(M)x4(N); per-wave C = 128x64.
// LDS layout: [2 buf][256 rows][64 cols] bf16, rows = 128B.
// Swizzle (read side): elem_vec_col = (fh ^ (fr&7)) ^ (kk*4).
// Write side: linear LDS dest + inverse-swizzled GLOBAL source
// (col_elems = ((l&7)^(l>>3))*8) -- same involution, rule #21.
// Staging: per phase each wave issues 2 global_load_lds (1KB stripes).
// Prefetch distance = 4 phases; vmcnt(6) each phase retires phase p-3.
// =====================================================================
template <int MH, int NH>
__device__ __forceinline__ void quad(f32x4 (&acc)[8][4],
                                     const bf16x8 (&aF)[4][2],
                                     const bf16x8 (&bF)[2][2]) {
#pragma unroll
  for (int mi = 0; mi < 4; ++mi)
#pragma unroll
    for (int ni = 0; ni < 2; ++ni)
#pragma unroll
      for (int kk = 0; kk < 2; ++kk)
        acc[MH * 4 + mi][NH * 2 + ni] = __builtin_amdgcn_mfma_f32_16x16x32_bf16(
            aF[mi][kk], bF[ni][kk], acc[MH * 4 + mi][NH * 2 + ni], 0, 0, 0);
}

__global__ __launch_bounds__(512, 2) void gemm256_8phase(
    const uint16_t* __restrict__ A, const uint16_t* __restrict__ B,
    const float* __restrict__ bias, float* __restrict__ C,
    int Mi, int Ni, int Ki) {
  __shared__ __align__(16) uint16_t As[2][256 * 64];  // 64 KB
  __shared__ __align__(16) uint16_t Bs[2][256 * 64];  // 64 KB

  const int tid = threadIdx.x;
  const int l   = tid & 63;
  const int wv  = tid >> 6;
  const int wr  = wv >> 2;   // 0..1
  const int wc  = wv & 3;    // 0..3
  const int fr  = l & 15;
  const int fh  = l >> 4;
  const int l8  = l >> 3;
  const int l7  = l & 7;

  const int nbm = Mi >> 8, nbn = Ni >> 8;
  const int nwg = nbm * nbn;
  // bijective XCD swizzle (m204)
  const int q = nwg >> 3, r = nwg & 7;
  const int xcd = (int)blockIdx.x & 7, orig = (int)blockIdx.x >> 3;
  const int swz = (xcd < r ? xcd * (q + 1) : r * (q + 1) + (xcd - r) * q) + orig;
  const int bm = swz / nbn;
  const int bn = swz % nbn;

  // ---- staging source bases (per-lane, inverse-swizzled col) ----
  const int xcol = (l7 ^ l8) << 3;  // elems within row
  const uint16_t* gA0 = A + (size_t)((bm << 8) + (wv << 3) + l8) * Ki + xcol;
  const int bw0 = ((wv & 3) << 3) + ((wv >> 2) << 6);  // B stripe wave base row
  const uint16_t* gB0 = B + (size_t)((bn << 8) + bw0 + l8) * Ki + xcol;

#define STAGE_A(bufi, chunk, t)                              \
  gload_lds16(gA0 + (size_t)(chunk) * Ki + (t) * 64,         \
              &As[bufi][(size_t)((chunk) + (wv << 3)) << 6])
#define STAGE_B(bufi, roff, t)                               \
  gload_lds16(gB0 + (size_t)(roff) * Ki + (t) * 64,          \
              &Bs[bufi][(size_t)(bw0 + (roff)) << 6])

  // ---- swizzled read-side fragment addressing ----
  const int ac0 = fh ^ (fr & 7);  // vec-col for kk=0; kk=1 -> ac0^4
  const bf16x8* Av = reinterpret_cast<const bf16x8*>(&As[0][0]);
  const bf16x8* Bv = reinterpret_cast<const bf16x8*>(&Bs[0][0]);
  constexpr int TILE_V = (256 * 64) / 8;  // 2048 vectors per buffer

#define LDA_(bufi, mh, mi, kk)                                              \
  Av[(bufi) * TILE_V + (((wr << 7) + ((mh) << 6) + ((mi) << 4) + fr) << 3) + \
     (ac0 ^ ((kk) << 2))]
#define LDB_(bufi, nh, ni, kk)                                              \
  Bv[(bufi) * TILE_V + (((wc << 6) + ((nh) << 5) + ((ni) << 4) + fr) << 3) + \
     (ac0 ^ ((kk) << 2))]

  f32x4 acc[8][4] = {};
  bf16x8 aF[4][2], b0[2][2], b1[2][2];

  const int NT = Ki >> 6;   // K-tiles (even: Ki % 128 == 0 guaranteed by host)
  const int NI = NT >> 1;   // iterations

  // ---- prologue: tile0 x8 + tile1 {A00,B00}; first 4 = phase-1 needs ----
  STAGE_A(0, 0, 0);
  STAGE_B(0, 0, 0);
  STAGE_A(0, 128, 0);
  STAGE_B(0, 128, 0);
  STAGE_B(0, 32, 0);
  STAGE_B(0, 160, 0);
  STAGE_A(0, 64, 0);
  STAGE_A(0, 192, 0);
  STAGE_A(1, 0, 1);
  STAGE_B(1, 0, 1);
  asm volatile("s_waitcnt vmcnt(6)" ::: "memory");
  __builtin_amdgcn_sched_barrier(0);
  BARRIER();

#pragma unroll 1
  for (int i = 0; i < NI; ++i) {
    const int t1 = 2 * i + 1, t2 = 2 * i + 2, t3 = 2 * i + 3;
    const bool g2 = (t2 < NT), g3 = (t3 < NT);

    // ---- phase 1: tile 2i (buf0) Q(0,0); reads A-mh0 + B-nh0 (12) ----
#pragma unroll
    for (int mi = 0; mi < 4; ++mi) {
      aF[mi][0] = LDA_(0, 0, mi, 0);
      aF[mi][1] = LDA_(0, 0, mi, 1);
    }
#pragma unroll
    for (int ni = 0; ni < 2; ++ni) {
      b0[ni][0] = LDB_(0, 0, ni, 0);
      b0[ni][1] = LDB_(0, 0, ni, 1);
    }
    STAGE_A(1, 128, t1);
    STAGE_B(1, 128, t1);
    VM6();
    BARRIER();
    LGKM0();
    __builtin_amdgcn_s_setprio(1);
    quad<0, 0>(acc, aF, b0);
    __builtin_amdgcn_s_setprio(0);
    BARRIER();

    // ---- phase 2: Q(0,1); reads B-nh1 (4) ----
#pragma unroll
    for (int ni = 0; ni < 2; ++ni) {
      b1[ni][0] = LDB_(0, 1, ni, 0);
      b1[ni][1] = LDB_(0, 1, ni, 1);
    }
    STAGE_B(1, 32, t1);
    STAGE_B(1, 160, t1);
    VM6();
    BARRIER();
    LGKM0();
    __builtin_amdgcn_s_setprio(1);
    quad<0, 1>(acc, aF, b1);
    __builtin_amdgcn_s_setprio(0);
    BARRIER();

    // ---- phase 3: Q(1,0); reads A-mh1 (8) ----
#pragma unroll
    for (int mi = 0; mi < 4; ++mi) {
      aF[mi][0] = LDA_(0, 1, mi, 0);
      aF[mi][1] = LDA_(0, 1, mi, 1);
    }
    STAGE_A(1, 64, t1);
    STAGE_A(1, 192, t1);
    VM6();
    BARRIER();
    LGKM0();
    __builtin_amdgcn_s_setprio(1);
    quad<1, 0>(acc, aF, b0);
    __builtin_amdgcn_s_setprio(0);
    BARRIER();

    // ---- phase 4: Q(1,1); no reads ----
    if (g2) {
      STAGE_A(0, 0, t2);
      STAGE_B(0, 0, t2);
    }
    VM6();
    BARRIER();
    LGKM0();
    __builtin_amdgcn_s_setprio(1);
    quad<1, 1>(acc, aF, b1);
    __builtin_amdgcn_s_setprio(0);
    BARRIER();

    // ---- phase 5: tile 2i+1 (buf1) Q(0,0) ----
#pragma unroll
    for (int mi = 0; mi < 4; ++mi) {
      aF[mi][0] = LDA_(1, 0, mi, 0);
      aF[mi][1] = LDA_(1, 0, mi, 1);
    }
#pragma unroll
    for (int ni = 0; ni < 2; ++ni) {
      b0[ni][0] = LDB_(1, 0, ni, 0);
      b0[ni][1] = LDB_(1, 0, ni, 1);
    }
    if (g2) {
      STAGE_A(0, 128, t2);
      STAGE_B(0, 128, t2);
    }
    VM6();
    BARRIER();
    LGKM0();
    __builtin_amdgcn_s_setprio(1);
    quad<0, 0>(acc, aF, b0);
    __builtin_amdgcn_s_setprio(0);
    BARRIER();

    // ---- phase 6: Q(0,1) ----
#pragma unroll
    for (int ni = 0; ni < 2; ++ni) {
      b1[ni][0] = LDB_(1, 1, ni, 0);
      b1[ni][1] = LDB_(1, 1, ni, 1);
    }
    if (g2) {
      STAGE_B(0, 32, t2);
      STAGE_B(0, 160, t2);
    }
    VM6();
    BARRIER();
    LGKM0();
    __builtin_amdgcn_s_setprio(1);
    quad<0, 1>(acc, aF, b1);
    __builtin_amdgcn_s_setprio(0);
    BARRIER();

    // ---- phase 7: Q(1,0) ----
#pragma unroll
    for (int mi = 0; mi < 4; ++mi) {
      aF[mi][0] = LDA_(1, 1, mi, 0);
      aF[mi][1] = LDA_(1, 1, mi, 1);
    }
    if (g2) {
      STAGE_A(0, 64, t2);
      STAGE_A(0, 192, t2);
    }
    VM6();
    BARRIER();
    LGKM0();
    __builtin_amdgcn_s_setprio(1);
    quad<1, 0>(acc, aF, b0);
    __builtin_amdgcn_s_setprio(0);
    BARRIER();

    // ---- phase 8: Q(1,1) ----
    if (g3) {
      STAGE_A(1, 0, t3);
      STAGE_B(1, 0, t3);
    }
    VM6();
    BARRIER();
    LGKM0();
    __builtin_amdgcn_s_setprio(1);
    quad<1, 1>(acc, aF, b1);
    __builtin_amdgcn_s_setprio(0);
    BARRIER();
  }

  // ---- epilogue: scale + bias, C/D layout col=fr, row=fh*4+j ----
  const int rowB = (bm << 8) + (wr << 7);
  const int colB = (bn << 8) + (wc << 6);
#pragma unroll
  for (int n = 0; n < 4; ++n) {
    const int col = colB + n * 16 + fr;
    const float bv = bias[col];
#pragma unroll
    for (int m = 0; m < 8; ++m) {
      const int row = rowB + m * 16 + fh * 4;
#pragma unroll
      for (int j = 0; j < 4; ++j)
        C[(size_t)(row + j) * Ni + col] = acc[m][n][j] * kScale + bv;
    }
  }
}

// =====================================================================
// proven 128x128 fallback (round-1 kernel) for non-conforming shapes
// =====================================================================
__global__ __launch_bounds__(256) void gemm_bf16_bias(
    const uint16_t* __restrict__ A, const uint16_t* __restrict__ B,
    const float* __restrict__ bias, float* __restrict__ C,
    int Mi, int Ni, int Ki) {
  __shared__ __align__(16) uint16_t As[128 * 32];
  __shared__ __align__(16) uint16_t Bs[128 * 32];

  const int tid  = threadIdx.x;
  const int lane = tid & 63;
  const int wv   = tid >> 6;
  const int wr   = wv >> 1;
  const int wc   = wv & 1;
  const int fr   = lane & 15;
  const int fh   = lane >> 4;

  const int nTilesN = Ni >> 7;
  const int nwg = gridDim.x;
  const int q = nwg >> 3, r = nwg & 7;
  const int xcd = (int)blockIdx.x & 7, orig = (int)blockIdx.x >> 3;
  const int swz = (xcd < r ? xcd * (q + 1) : r * (q + 1) + (xcd - r) * q) + orig;
  const int bm = swz / nTilesN;
  const int bn = swz % nTilesN;

  const int sRow = tid >> 2;
  const int sCol = (tid & 3) << 3;

  const uint16_t* gA0 = A + (size_t)(bm * 128 + sRow) * Ki + sCol;
  const uint16_t* gA1 = gA0 + (size_t)64 * Ki;
  const uint16_t* gB0 = B + (size_t)(bn * 128 + sRow) * Ki + sCol;
  const uint16_t* gB1 = gB0 + (size_t)64 * Ki;
  uint16_t* lA0 = &As[tid * 8];
  uint16_t* lA1 = &As[(256 + tid) * 8];
  uint16_t* lB0 = &Bs[tid * 8];
  uint16_t* lB1 = &Bs[(256 + tid) * 8];

  const bf16x8* Av = reinterpret_cast<const bf16x8*>(As);
  const bf16x8* Bv = reinterpret_cast<const bf16x8*>(Bs);

  f32x4 acc[4][4] = {};

  for (int k0 = 0; k0 < Ki; k0 += 32) {
    gload_lds16(gA0 + k0, lA0);
    gload_lds16(gA1 + k0, lA1);
    gload_lds16(gB0 + k0, lB0);
    gload_lds16(gB1 + k0, lB1);
    __syncthreads();

    bf16x8 af[4], bfr[4];
#pragma unroll
    for (int m = 0; m < 4; ++m) af[m] = Av[(wr * 64 + m * 16 + fr) * 4 + fh];
#pragma unroll
    for (int n = 0; n < 4; ++n) bfr[n] = Bv[(wc * 64 + n * 16 + fr) * 4 + fh];

#pragma unroll
    for (int m = 0; m < 4; ++m)
#pragma unroll
      for (int n = 0; n < 4; ++n)
        acc[m][n] = __builtin_amdgcn_mfma_f32_16x16x32_bf16(af[m], bfr[n],
                                                            acc[m][n], 0, 0, 0);
    __syncthreads();
  }

  const int rowBase = bm * 128 + wr * 64;
  const int colBase = bn * 128 + wc * 64;
#pragma unroll
  for (int n = 0; n < 4; ++n) {
    const int col = colBase + n * 16 + fr;
    const float bv = bias[col];
#pragma unroll
    for (int m = 0; m < 4; ++m) {
      const int row = rowBase + m * 16 + fh * 4;
#pragma unroll
      for (int j = 0; j < 4; ++j)
        C[(size_t)(row + j) * Ni + col] = acc[m][n][j] * kScale + bv;
    }
  }
}

// ---------- fallback: naive f32 ----------
__global__ void naive_gemm(const float* __restrict__ x, const float* __restrict__ w,
                           const float* __restrict__ bias, float* __restrict__ out,
                           int Mi, int Ni, int Ki) {
  long idx = (long)blockIdx.x * blockDim.x + threadIdx.x;
  if (idx >= (long)Mi * Ni) return;
  int m = (int)(idx / Ni), n = (int)(idx % Ni);
  float s = 0.f;
  for (int k = 0; k < Ki; ++k) s += x[(long)m * Ki + k] * w[(long)n * Ki + k];
  out[idx] = s * kScale + bias[n];
}

extern "C" void kernel_launch(void* const* d_in, const int* in_sizes, int n_in,
                              void* d_out, int out_size, void* d_ws, size_t ws_size,
                              hipStream_t stream) {
  const float* x    = (const float*)d_in[0];
  const float* w    = (const float*)d_in[1];
  const float* bias = (const float*)d_in[2];
  float* out = (float*)d_out;

  const int Ni = in_sizes[2];
  const int Ki = in_sizes[1] / Ni;
  const int Mi = in_sizes[0] / Ki;

  const size_t nx = (size_t)Mi * Ki;
  const size_t nw = (size_t)Ni * Ki;

  if (ws_size >= (nx + nw) * sizeof(uint16_t) && (Ki % 32) == 0 &&
      (Mi % 128) == 0 && (Ni % 128) == 0) {
    uint16_t* xb = (uint16_t*)d_ws;
    uint16_t* wb = xb + nx;
    cvt_f32_to_bf16<<<(int)(nx / 2048), 256, 0, stream>>>(x, (uint4*)xb);
    cvt_f32_to_bf16<<<(int)(nw / 2048), 256, 0, stream>>>(w, (uint4*)wb);

    if ((Mi % 256) == 0 && (Ni % 256) == 0 && (Ki % 128) == 0) {
      dim3 grid((Mi / 256) * (Ni / 256));
      gemm256_8phase<<<grid, 512, 0, stream>>>(xb, wb, bias, out, Mi, Ni, Ki);
    } else {
      dim3 grid((Mi / 128) * (Ni / 128));
      gemm_bf16_bias<<<grid, 256, 0, stream>>>(xb, wb, bias, out, Mi, Ni, Ki);
    }
  } else {
    long total = (long)Mi * Ni;
    naive_gemm<<<(int)((total + 255) / 256), 256, 0, stream>>>(x, w, bias, out,
                                                               Mi, Ni, Ki);
  }
}